// Round 4
// baseline (159.351 us; speedup 1.0000x reference)
//
#include <hip/hip_runtime.h>
#include <math.h>

#define N_TRIAL 1000000
#define N_REF 8
#define N_DIM 16
#define N_GROUP 4
#define BETA 1.0f
#define GAMMA 0.001f
// N_SELECT = {1,2,3,1} packed as nibbles: idx 0->1, 1->2, 2->3, 3->1
#define N_SELECT_PACKED 0x1321

typedef float v4f __attribute__((ext_vector_type(4)));

#define WAVES_PER_BLOCK 4
// LDS row stride (dwords) for the [ref][trial] transpose buffer.
// 72 = 64 + 8: write banks = (16s + 16j + q) % 32 -> exactly 2-way (free);
// read banks = (8r + lane) % 32, consecutive lanes -> 2-way (free).
#define ROW_STRIDE 72

// Hybrid two-phase wave: phase 1 = quad-per-trial gather+distance (keeps the
// round-3 coalescing win: one gather inst covers 16 rows / 16 cache lines);
// phase 2 = thread-per-trial tail (de-replicates the 4x-redundant sqrt/exp/
// suffix/product work that made round 3 VALU-bound at 63% VALUBusy).
__global__ __launch_bounds__(256, 4) void likelihood_kernel(
    const int* __restrict__ stim,     // N_TRIAL x (N_REF+1)
    const int* __restrict__ config,   // N_TRIAL
    const int* __restrict__ group,    // N_TRIAL
    const int* __restrict__ present,  // N_TRIAL x (N_REF+1)
    const float* __restrict__ embed,  // N_STIM x N_DIM
    const float* __restrict__ attw,   // N_GROUP x N_DIM
    float* __restrict__ out)          // N_TRIAL
{
    __shared__ float d2buf[WAVES_PER_BLOCK][N_REF][ROW_STRIDE];

    const int tid  = threadIdx.x;
    const int wv   = tid >> 6;
    const int lane = tid & 63;
    const int q    = lane >> 2;   // quad id 0..15
    const int s    = lane & 3;    // float4 segment 0..3

    const int wtb = blockIdx.x * 256 + wv * 64;   // this wave's 64 trials

    const float* embed_s = embed + s * 4;         // per-lane segment base

    float* row_a = &d2buf[wv][2 * s][0];
    float* row_b = &d2buf[wv][2 * s + 1][0];

    // ---------------- Phase 1: quad layout, 4 iterations x 16 trials -------
    for (int j = 0; j < 4; ++j) {
        int t  = wtb + 16 * j + q;
        int tc = (t < N_TRIAL) ? t : (N_TRIAL - 1);   // clamp for tail block

        const int* sp = stim + tc * (N_REF + 1);
        const int* pp = present + tc * (N_REF + 1);

        int idx[N_REF + 1];
#pragma unroll
        for (int i = 0; i <= N_REF; ++i) idx[i] = sp[i];

        int pr[N_REF];
#pragma unroll
        for (int r = 0; r < N_REF; ++r) pr[r] = pp[1 + r];

        int g = group[tc];
        // attw is 256 B total -> L1-resident after first touch
        v4f w  = *(const v4f*)(attw + g * N_DIM + s * 4);
        v4f zq = *(const v4f*)(embed_s + idx[0] * N_DIM);

#pragma unroll
        for (int r = 0; r < N_REF; ++r) {
            v4f zr = *(const v4f*)(embed_s + idx[1 + r] * N_DIM);
            v4f dd = zq - zr;
            v4f p  = w * dd * dd;
            float d2 = (p.x + p.y) + (p.z + p.w);
            // quad butterfly: full 16-dim sum lands in all 4 lanes
            d2 += __shfl_xor(d2, 1);
            d2 += __shfl_xor(d2, 2);
            // fold present mask into d2 as a sentinel (phase 2 maps <0 -> sim=0)
            d2 = (pr[r] != 0) ? d2 : -1.0f;
            // lane s persists rows 2s and 2s+1 (uses the quad replication)
            if (r == 2 * s)     row_a[16 * j + q] = d2;
            if (r == 2 * s + 1) row_b[16 * j + q] = d2;
        }
    }

    __syncthreads();   // publish LDS transpose (also orders ds_write/ds_read)

    // ---------------- Phase 2: thread-per-trial tail -----------------------
    int t2  = wtb + lane;
    int t2c = (t2 < N_TRIAL) ? t2 : (N_TRIAL - 1);

    float sim[N_REF];
#pragma unroll
    for (int r = 0; r < N_REF; ++r) {
        float d2 = d2buf[wv][r][lane];
        float e  = __expf(-BETA * sqrtf(d2)) + GAMMA;
        sim[r] = (d2 < 0.0f) ? 0.0f : e;
    }

    int c  = config[t2c];
    int ns = (N_SELECT_PACKED >> ((c & 3) * 4)) & 0xF;   // ns in {1,2,3}

    // only suffix[0..2] are ever selected (max N_SELECT == 3)
    float suf2 = sim[7];
#pragma unroll
    for (int r = 6; r >= 2; --r) suf2 += sim[r];
    float suf1 = suf2 + sim[1];
    float suf0 = suf1 + sim[0];

    // lik = prod_{r<ns} sim[r]/suffix[r] ; ns>=1 always -> one division total
    float num = sim[0] * ((ns >= 2) ? sim[1] : 1.0f) * ((ns >= 3) ? sim[2] : 1.0f);
    float den = suf0   * ((ns >= 2) ? suf1   : 1.0f) * ((ns >= 3) ? suf2   : 1.0f);

    if (t2 < N_TRIAL)
        out[t2] = __fdividef(num, den);   // fully coalesced store
}

extern "C" void kernel_launch(void* const* d_in, const int* in_sizes, int n_in,
                              void* d_out, int out_size, void* d_ws, size_t ws_size,
                              hipStream_t stream) {
    const int*   stim    = (const int*)d_in[0];
    const int*   config  = (const int*)d_in[1];
    const int*   group   = (const int*)d_in[2];
    const int*   present = (const int*)d_in[3];
    const float* embed   = (const float*)d_in[4];
    const float* attw    = (const float*)d_in[5];
    float*       out     = (float*)d_out;

    int blocks = (N_TRIAL + 255) / 256;   // 256 trials per block (64 per wave)
    likelihood_kernel<<<blocks, 256, 0, stream>>>(stim, config, group, present,
                                                  embed, attw, out);
}

// Round 5
// 139.791 us; speedup vs baseline: 1.1399x; 1.1399x over previous
//
#include <hip/hip_runtime.h>
#include <math.h>

#define N_TRIAL 1000000
#define N_REF 8
#define N_DIM 16
#define N_GROUP 4
#define BETA 1.0f
#define GAMMA 0.001f
// N_SELECT = {1,2,3,1} packed as nibbles
#define N_SELECT_PACKED 0x1321

#define WPB 4          // waves per block
#define D2_STRIDE 72   // 64+8: writes (16s+q)%32 and reads (8r+lane)%32 both 2-way = free

typedef float v4f  __attribute__((ext_vector_type(4)));
typedef int   v4iu __attribute__((ext_vector_type(4), aligned(4)));  // dword-aligned int4

// Per-wave, barrier-free two-phase kernel.
//   staging : wave's 64 stim rows (2304 B) copied dense+coalesced into LDS
//             (3 dwordx4 insts; each stream cache line touched ONCE vs ~9x
//              in the scattered layouts of rounds 1-4 -- the measured TA wall)
//   phase 1 : quad-per-trial gathers (9 lines/trial = floor) + weighted dist
//   phase 2 : thread-per-trial tail (no 4x replication of sqrt/exp/suffix)
// All LDS dependencies are intra-wave -> no __syncthreads, no inter-wave
// coupling (the round-4 regression). 4.6 KB LDS/wave -> 8 blocks/CU.
__global__ __launch_bounds__(256) void likelihood_kernel(
    const int* __restrict__ stim,     // N_TRIAL x 9
    const int* __restrict__ config,   // N_TRIAL
    const int* __restrict__ group,    // N_TRIAL
    const int* __restrict__ present,  // N_TRIAL x 9
    const float* __restrict__ embed,  // N_STIM x 16
    const float* __restrict__ attw,   // N_GROUP x 16
    float* __restrict__ out)          // N_TRIAL
{
    __shared__ int4  s_stim4[WPB][144];            // 64 trials x 9 ints, dense
    __shared__ float s_d2[WPB][N_REF][D2_STRIDE];  // [ref][trial] transpose

    const int tid  = threadIdx.x;
    const int wv   = tid >> 6;
    const int lane = tid & 63;
    const int q    = lane >> 2;   // quad id 0..15
    const int s    = lane & 3;    // float4 segment 0..3

    int wtb = blockIdx.x * 256 + wv * 64;          // this wave's 64 trials
    const bool valid = (wtb + lane) < N_TRIAL;
    if (wtb > N_TRIAL - 64) wtb = N_TRIAL - 64;    // N_TRIAL % 64 == 0

    // ---- dense coalesced staging of stim (16B-aligned: 64*9*4 = 2304) ----
    {
        const int4* g4 = (const int4*)(stim + wtb * 9);   // 144 int4 per wave
        s_stim4[wv][lane]      = g4[lane];
        s_stim4[wv][64 + lane] = g4[64 + lane];
        if (lane < 16) s_stim4[wv][128 + lane] = g4[128 + lane];
    }

    // ---- coalesced stream loads, issued early to fly under phase 1 ----
    const int t2 = wtb + lane;                     // phase-2 trial (always valid addr)
    const int* pp = present + t2 * 9;
    v4iu p0 = *(const v4iu*)(pp + 1);              // present[1..4]
    v4iu p1 = *(const v4iu*)(pp + 5);              // present[5..8]
    int  c    = config[t2];
    int  gall = group[t2];                         // redistributed via __shfl below

    const float* embed_s = embed + s * 4;          // this lane's row segment

    // ---------------- Phase 1: quad layout, 4 passes x 16 trials ----------
    for (int j = 0; j < 4; ++j) {
        const int* sp = (const int*)&s_stim4[wv][0] + (16 * j + q) * 9;
        int idx[9];
#pragma unroll
        for (int i = 0; i < 9; ++i) idx[i] = sp[i];   // conflict-free banks

        int g  = __shfl(gall, 16 * j + q);            // quad-uniform group id
        v4f w  = *(const v4f*)(attw + g * N_DIM + s * 4);   // 256B, L1-hot
        v4f zq = *(const v4f*)(embed_s + idx[0] * N_DIM);

        float d2v[N_REF];
#pragma unroll
        for (int r = 0; r < N_REF; ++r) {
            v4f zr = *(const v4f*)(embed_s + idx[1 + r] * N_DIM);
            v4f dd = zq - zr;
            v4f wd = w * dd;
            float d2 = (wd.x * dd.x + wd.y * dd.y) + (wd.z * dd.z + wd.w * dd.w);
            d2 += __shfl_xor(d2, 1);   // quad butterfly: full 16-dim sum
            d2 += __shfl_xor(d2, 2);
            d2v[r] = d2;
        }
        // lane s persists rows 2s, 2s+1 (uses the quad replication)
        float da = (s == 0) ? d2v[0] : (s == 1) ? d2v[2] : (s == 2) ? d2v[4] : d2v[6];
        float db = (s == 0) ? d2v[1] : (s == 1) ? d2v[3] : (s == 2) ? d2v[5] : d2v[7];
        s_d2[wv][2 * s    ][16 * j + q] = da;
        s_d2[wv][2 * s + 1][16 * j + q] = db;
    }
    // intra-wave ds_write -> ds_read ordering handled by compiler lgkmcnt;
    // no __syncthreads (all LDS state is per-wave).

    // ---------------- Phase 2: thread-per-trial tail -----------------------
    int pr[N_REF] = {p0.x, p0.y, p0.z, p0.w, p1.x, p1.y, p1.z, p1.w};

    float sim[N_REF];
#pragma unroll
    for (int r = 0; r < N_REF; ++r) {
        float d2 = s_d2[wv][r][lane];
        sim[r] = (__expf(-BETA * sqrtf(d2)) + GAMMA) * (float)pr[r];
    }

    int ns = (N_SELECT_PACKED >> ((c & 3) * 4)) & 0xF;   // ns in {1,2,3}

    // only suffix[0..2] can be selected (max N_SELECT == 3)
    float suf2 = sim[7];
#pragma unroll
    for (int r = 6; r >= 2; --r) suf2 += sim[r];
    float suf1 = suf2 + sim[1];
    float suf0 = suf1 + sim[0];

    float num = sim[0] * ((ns >= 2) ? sim[1] : 1.0f) * ((ns >= 3) ? sim[2] : 1.0f);
    float den = suf0   * ((ns >= 2) ? suf1   : 1.0f) * ((ns >= 3) ? suf2   : 1.0f);

    if (valid)
        out[wtb + lane] = __fdividef(num, den);   // fully coalesced store
}

extern "C" void kernel_launch(void* const* d_in, const int* in_sizes, int n_in,
                              void* d_out, int out_size, void* d_ws, size_t ws_size,
                              hipStream_t stream) {
    const int*   stim    = (const int*)d_in[0];
    const int*   config  = (const int*)d_in[1];
    const int*   group   = (const int*)d_in[2];
    const int*   present = (const int*)d_in[3];
    const float* embed   = (const float*)d_in[4];
    const float* attw    = (const float*)d_in[5];
    float*       out     = (float*)d_out;

    int blocks = (N_TRIAL + 255) / 256;   // 3907; tail handled by clamp+valid
    likelihood_kernel<<<blocks, 256, 0, stream>>>(stim, config, group, present,
                                                  embed, attw, out);
}